// Round 11
// baseline (303.869 us; speedup 1.0000x reference)
//
#include <hip/hip_runtime.h>
#include <stdint.h>

// R17: the untested quadrant — 3 INDEPENDENT blocks/CU with a spill-clean
// 16-acc kernel. R13/R16 plateau at ~154us with 2 blocks/CU proves phase
// content isn't the wall; overlap is. Both binding constraints relaxed:
//   LDS: drop act dbuf (in-place + 2 WAR barriers, 4->6 barriers) and give
//     L4 a separate 16KB h4L output buffer (no WAR there). 50.4KB/block ->
//     3 blocks = 151KB < 160KB.
//   Regs: __launch_bounds__(256,3) = 168 total (104 arch + 64 acc). B
//     prefetch becomes ping-pong depth-2 under '#pragma unroll 1' (32 regs,
//     structurally capped -- compiler can't hoist across unroll-1, the R9
//     proven-spill-free mechanism). Worst phase ~137 << 168.
// Tripwire: WRITE<30MB (else 104-arch infeasible -> revert R16+micro).
// Clean but >=150us -> occupancy conclusively null -> R13/R16 is the floor.
// Predict: LDS ~50.5K, VGPR<=104, occ ~27-30%, kernel 155.7 -> 115-135us.

#define NRAYS 4096

typedef unsigned short u16;
typedef __attribute__((ext_vector_type(8))) short short8;
typedef __attribute__((ext_vector_type(4))) float f32x4;

__device__ __forceinline__ u16 f2bf(float f) {
  union { float f; uint32_t i; } v; v.f = f;
  return (u16)((v.i + 0x7FFFu + ((v.i >> 16) & 1u)) >> 16);
}
__device__ __forceinline__ float bf2f(u16 u) {
  union { uint32_t i; float f; } v; v.i = ((uint32_t)u) << 16; return v.f;
}
// packed fp32->bf16 (RNE), lo -> bits 15:0, hi -> bits 31:16 (bit-identical to f2bf)
__device__ __forceinline__ uint32_t cvtpk(float lo, float hi) {
  uint32_t r;
  asm("v_cvt_pk_bf16_f32 %0, %1, %2" : "=v"(r) : "v"(lo), "v"(hi));
  return r;
}

// stratified z sample for slot j (MUST stay textually identical everywhere)
__device__ __forceinline__ float zval(int j, float tr) {
  float fj = (float)j;
  float zj = 0.5f + 2.0f * (fj / 63.0f);
  float lower = (j == 0)  ? zj : 0.5f * (zj + (0.5f + 2.0f * ((fj - 1.0f) / 63.0f)));
  float upper = (j == 63) ? zj : 0.5f * (zj + (0.5f + 2.0f * ((fj + 1.0f) / 63.0f)));
  return lower + (upper - lower) * tr;
}

// fragment-contiguous index for a [N][K=256] tile (8 kq blocks)
__device__ __forceinline__ int fragidx(int n, int k) {
  return ((((n >> 4) * 8 + (k >> 5)) * 64 + ((k >> 3) & 3) * 16 + (n & 15)) << 3) + (k & 7);
}
// same for a [N][K=32] tile (1 kq block)
__device__ __forceinline__ int fragidx32(int n, int k) {
  return (((n >> 4) * 64 + ((k >> 3) & 3) * 16 + (n & 15)) << 3) + (k & 7);
}

// ---------------- weight pack (fp32 -> bf16 fragment tiles) ----------------
// ws (bf16 elems): W2f @0 (65536), W3f @65536 (65536), W4f @131072 (32768),
//   Wd-pad @163840 (4096: [256K][16N] col0=Wd), W5-pad @167936 (2048),
//   W1-pad @169984 (8192: [256N][32K], k0/1=W1r0, k2/3=W1r1, k4/5=W1r2, k6=b1)
__global__ void pack_weights(const float* __restrict__ W1, const float* __restrict__ b1,
                             const float* __restrict__ W2, const float* __restrict__ W3,
                             const float* __restrict__ W4, const float* __restrict__ Wd,
                             const float* __restrict__ W5, u16* __restrict__ ws) {
  int idx = blockIdx.x * 256 + threadIdx.x;   // grid covers exactly 178176
  float v;
  int dst;
  if (idx < 65536) {
    int k = idx >> 8, n = idx & 255;          // W2 row-major [k][n]
    v = W2[idx];
    dst = fragidx(n, k);
  } else if (idx < 131072) {
    int o = idx - 65536, k = o >> 8, n = o & 255;
    v = W3[o];
    dst = 65536 + fragidx(n, k);
  } else if (idx < 163840) {
    int o = idx - 131072, k = o >> 7, n = o & 127;  // W4 row-major [k][128]
    v = W4[o];
    dst = 131072 + fragidx(n, k);
  } else if (idx < 167936) {
    int o = idx - 163840, k = o >> 4, n = o & 15;   // Wd [256][1] padded to 16 cols
    v = (n == 0) ? Wd[k] : 0.f;
    dst = 163840 + fragidx(n, k);
  } else if (idx < 169984) {
    int o = idx - 167936, k = o >> 4, n = o & 15;   // W5 [128][3] padded to 16 cols
    v = (n < 3) ? W5[k * 3 + n] : 0.f;
    dst = 167936 + fragidx(n, k);
  } else {
    int o = idx - 169984, k = o >> 8, n = o & 255;  // W1-pad [256N][32K]
    if (k < 6)      v = W1[(k >> 1) * 256 + n];     // k0/1: row0; k2/3: row1; k4/5: row2
    else if (k == 6) v = b1[n];
    else            v = 0.f;
    dst = 169984 + fragidx32(n, k);
  }
  ws[dst] = f2bf(v);
}

#define MFMA __builtin_amdgcn_mfma_f32_16x16x32_bf16
#define ZER4 (f32x4){0.f, 0.f, 0.f, 0.f}

// declare + load the 4 A row-tile fragments for k-slice SQ from act [64][256]
#define LDA4(SQ)                                                               \
    short8 av0 = *(const short8*)(act + m0 * 256 + (((SQ) ^ (m0 & 31)) << 3)); \
    short8 av1 = *(const short8*)(act + m1 * 256 + (((SQ) ^ (m1 & 31)) << 3)); \
    short8 av2 = *(const short8*)(act + m2 * 256 + (((SQ) ^ (m2 & 31)) << 3)); \
    short8 av3 = *(const short8*)(act + m3 * 256 + (((SQ) ^ (m3 & 31)) << 3))

// 16 MFMA: 4 row-tiles (av0..av3) x 4 B col-tiles
#define MF16v(B0, B1, B2_, B3_) do {                                         \
    c00 = MFMA(av0, B0, c00, 0, 0, 0); c10 = MFMA(av1, B0, c10, 0, 0, 0);    \
    c20 = MFMA(av2, B0, c20, 0, 0, 0); c30 = MFMA(av3, B0, c30, 0, 0, 0);    \
    c01 = MFMA(av0, B1, c01, 0, 0, 0); c11 = MFMA(av1, B1, c11, 0, 0, 0);    \
    c21 = MFMA(av2, B1, c21, 0, 0, 0); c31 = MFMA(av3, B1, c31, 0, 0, 0);    \
    c02 = MFMA(av0, B2_, c02, 0, 0, 0); c12 = MFMA(av1, B2_, c12, 0, 0, 0);  \
    c22 = MFMA(av2, B2_, c22, 0, 0, 0); c32 = MFMA(av3, B2_, c32, 0, 0, 0);  \
    c03 = MFMA(av0, B3_, c03, 0, 0, 0); c13 = MFMA(av1, B3_, c13, 0, 0, 0);  \
    c23 = MFMA(av2, B3_, c23, 0, 0, 0); c33 = MFMA(av3, B3_, c33, 0, 0, 0);  \
  } while (0)

// 12 MFMA: 4 row-tiles x (2 B col-tiles + density col)
#define MF12v(B0, B1, BD) do {                                               \
    c00 = MFMA(av0, B0, c00, 0, 0, 0); c10 = MFMA(av1, B0, c10, 0, 0, 0);    \
    c20 = MFMA(av2, B0, c20, 0, 0, 0); c30 = MFMA(av3, B0, c30, 0, 0, 0);    \
    c01 = MFMA(av0, B1, c01, 0, 0, 0); c11 = MFMA(av1, B1, c11, 0, 0, 0);    \
    c21 = MFMA(av2, B1, c21, 0, 0, 0); c31 = MFMA(av3, B1, c31, 0, 0, 0);    \
    c40 = MFMA(av0, BD, c40, 0, 0, 0); c41 = MFMA(av1, BD, c41, 0, 0, 0);    \
    c42 = MFMA(av2, BD, c42, 0, 0, 0); c43 = MFMA(av3, BD, c43, 0, 0, 0);    \
  } while (0)

// store one 16x16 C-tile into act [64][256] (32 swizzle slots)
#define EPIC(CV, mt, ng, addv) do {                                          \
    int su_ = ((ng) >> 3), so_ = ((ng) & 7);                                 \
    float f0_ = fmaxf((CV)[0] + (addv), 0.f);                                \
    float f1_ = fmaxf((CV)[1] + (addv), 0.f);                                \
    float f2_ = fmaxf((CV)[2] + (addv), 0.f);                                \
    float f3_ = fmaxf((CV)[3] + (addv), 0.f);                                \
    uint32_t p01_ = cvtpk(f0_, f1_), p23_ = cvtpk(f2_, f3_);                 \
    int mmb_ = (mt) * 16 + quad * 4;                                         \
    act[(mmb_ + 0) * 256 + ((su_ ^ ((mmb_ + 0) & 31)) << 3) + so_] = (u16)p01_;         \
    act[(mmb_ + 1) * 256 + ((su_ ^ ((mmb_ + 1) & 31)) << 3) + so_] = (u16)(p01_ >> 16); \
    act[(mmb_ + 2) * 256 + ((su_ ^ ((mmb_ + 2) & 31)) << 3) + so_] = (u16)p23_;         \
    act[(mmb_ + 3) * 256 + ((su_ ^ ((mmb_ + 3) & 31)) << 3) + so_] = (u16)(p23_ >> 16); \
  } while (0)

// store one 16x16 C-tile into h4L [64][128] (16 swizzle slots)
#define EPIH(CV, mt, ng, addv) do {                                          \
    int su_ = ((ng) >> 3), so_ = ((ng) & 7);                                 \
    float f0_ = fmaxf((CV)[0] + (addv), 0.f);                                \
    float f1_ = fmaxf((CV)[1] + (addv), 0.f);                                \
    float f2_ = fmaxf((CV)[2] + (addv), 0.f);                                \
    float f3_ = fmaxf((CV)[3] + (addv), 0.f);                                \
    uint32_t p01_ = cvtpk(f0_, f1_), p23_ = cvtpk(f2_, f3_);                 \
    int mmb_ = (mt) * 16 + quad * 4;                                         \
    h4L[(mmb_ + 0) * 128 + ((su_ ^ ((mmb_ + 0) & 15)) << 3) + so_] = (u16)p01_;         \
    h4L[(mmb_ + 1) * 128 + ((su_ ^ ((mmb_ + 1) & 15)) << 3) + so_] = (u16)(p01_ >> 16); \
    h4L[(mmb_ + 2) * 128 + ((su_ ^ ((mmb_ + 2) & 15)) << 3) + so_] = (u16)p23_;         \
    h4L[(mmb_ + 3) * 128 + ((su_ ^ ((mmb_ + 3) & 15)) << 3) + so_] = (u16)(p23_ >> 16); \
  } while (0)

// A-fragments from h4L [64][128], SQ in 0..15
#define LDA4H(SQ)                                                              \
    short8 av0 = *(const short8*)(h4L + m0 * 128 + (((SQ) ^ (m0 & 15)) << 3)); \
    short8 av1 = *(const short8*)(h4L + m1 * 128 + (((SQ) ^ (m1 & 15)) << 3)); \
    short8 av2 = *(const short8*)(h4L + m2 * 128 + (((SQ) ^ (m2 & 15)) << 3)); \
    short8 av3 = *(const short8*)(h4L + m3 * 128 + (((SQ) ^ (m3 & 15)) << 3))

__global__ void __launch_bounds__(256, 3) nerf_fused(
    const float* __restrict__ rays_o, const float* __restrict__ rays_d,
    const float* __restrict__ t_rand,
    const float* __restrict__ b2, const float* __restrict__ b3,
    const float* __restrict__ bd,
    const float* __restrict__ W4, const float* __restrict__ b4,
    const float* __restrict__ b5,
    const u16* __restrict__ wpack, float* __restrict__ out) {
  __shared__ u16   act[64 * 256];    // 32 KB, in-place across L1->L2->L3 (WAR barriers)
  __shared__ u16   h4L[64 * 128];    // 16 KB, L4 output (no WAR)
  __shared__ float dens[64];
  __shared__ float rgbL[64 * 4];

  const int t = threadIdx.x;
  const int lane = t & 63;
  const int wv = t >> 6;        // 0..3
  const int quad = lane >> 4;
  const int l15 = lane & 15;
  const int ray = blockIdx.x;
  const int m0 = l15, m1 = l15 + 16, m2 = l15 + 32, m3 = l15 + 48;

  // B ping-pong (depth 2, reused across layers) — 8 short8 = 32 VGPRs cap
  short8 Pa0, Pa1, Pa2, Pa3, Pb0, Pb1, Pb2, Pb3;

  // ---- prefetch W1 frag (16) + B2 kq0/1 into ping-pong (32) ----
  short8 W1f0, W1f1, W1f2, W1f3;
  {
    const u16* w1b = wpack + 169984 + (wv * 4) * 512 + lane * 8;
    W1f0 = *(const short8*)(w1b);
    W1f1 = *(const short8*)(w1b + 512);
    W1f2 = *(const short8*)(w1b + 1024);
    W1f3 = *(const short8*)(w1b + 1536);
  }
  const u16* q0 = wpack + (wv * 4 + 0) * 4096 + lane * 8;
  const u16* q1 = wpack + (wv * 4 + 1) * 4096 + lane * 8;
  const u16* q2 = wpack + (wv * 4 + 2) * 4096 + lane * 8;
  const u16* q3 = wpack + (wv * 4 + 3) * 4096 + lane * 8;
  Pa0 = *(const short8*)(q0);       Pa1 = *(const short8*)(q1);
  Pa2 = *(const short8*)(q2);       Pa3 = *(const short8*)(q3);
  Pb0 = *(const short8*)(q0 + 512); Pb1 = *(const short8*)(q1 + 512);
  Pb2 = *(const short8*)(q2 + 512); Pb3 = *(const short8*)(q3 + 512);

  const float rox = rays_o[ray * 3 + 0], roy = rays_o[ray * 3 + 1], roz = rays_o[ray * 3 + 2];
  const float rdx = rays_d[ray * 3 + 0], rdy = rays_d[ray * 3 + 1], rdz = rays_d[ray * 3 + 2];

  // ---- layer 1 via MFMA: A built in regs (hi/lo split) -> act ----
  {
    short8 avz = {0, 0, 0, 0, 0, 0, 0, 0};
    short8 av0 = avz, av1 = avz, av2 = avz, av3 = avz;
    if (quad == 0) {
#pragma unroll
      for (int r = 0; r < 4; r++) {
        int m = l15 + r * 16;
        float tr = t_rand[ray * 64 + m];
        float zm = zval(m, tr);
        float px = rox + rdx * zm, py = roy + rdy * zm, pz = roz + rdz * zm;
        u16 xh = f2bf(px); float xl = px - bf2f(xh);
        u16 yh = f2bf(py); float yl = py - bf2f(yh);
        u16 zh = f2bf(pz); float zl = pz - bf2f(zh);
        short8 f;
        f[0] = (short)xh; f[1] = (short)f2bf(xl);
        f[2] = (short)yh; f[3] = (short)f2bf(yl);
        f[4] = (short)zh; f[5] = (short)f2bf(zl);
        f[6] = (short)0x3F80; f[7] = 0;
        if (r == 0) av0 = f; else if (r == 1) av1 = f;
        else if (r == 2) av2 = f; else av3 = f;
      }
    }
    f32x4 c00 = ZER4, c01 = ZER4, c02 = ZER4, c03 = ZER4;
    f32x4 c10 = ZER4, c11 = ZER4, c12 = ZER4, c13 = ZER4;
    f32x4 c20 = ZER4, c21 = ZER4, c22 = ZER4, c23 = ZER4;
    f32x4 c30 = ZER4, c31 = ZER4, c32 = ZER4, c33 = ZER4;
    MF16v(W1f0, W1f1, W1f2, W1f3);
    int ng0 = wv * 64 + l15;
    EPIC(c00, 0, ng0, 0.f); EPIC(c10, 1, ng0, 0.f);
    EPIC(c20, 2, ng0, 0.f); EPIC(c30, 3, ng0, 0.f);
    EPIC(c01, 0, ng0 + 16, 0.f); EPIC(c11, 1, ng0 + 16, 0.f);
    EPIC(c21, 2, ng0 + 16, 0.f); EPIC(c31, 3, ng0 + 16, 0.f);
    EPIC(c02, 0, ng0 + 32, 0.f); EPIC(c12, 1, ng0 + 32, 0.f);
    EPIC(c22, 2, ng0 + 32, 0.f); EPIC(c32, 3, ng0 + 32, 0.f);
    EPIC(c03, 0, ng0 + 48, 0.f); EPIC(c13, 1, ng0 + 48, 0.f);
    EPIC(c23, 2, ng0 + 48, 0.f); EPIC(c33, 3, ng0 + 48, 0.f);
  }
  __syncthreads();                                          // barrier 1 (of 6)

  // ---- layer 2: h2 = relu(h1@W2 + b2) : in-place act ----
  {
    int ng0 = wv * 64 + l15;
    float bi0 = b2[ng0], bi1 = b2[ng0 + 16], bi2 = b2[ng0 + 32], bi3 = b2[ng0 + 48];
    f32x4 c00 = ZER4, c01 = ZER4, c02 = ZER4, c03 = ZER4;
    f32x4 c10 = ZER4, c11 = ZER4, c12 = ZER4, c13 = ZER4;
    f32x4 c20 = ZER4, c21 = ZER4, c22 = ZER4, c23 = ZER4;
    f32x4 c30 = ZER4, c31 = ZER4, c32 = ZER4, c33 = ZER4;
#pragma unroll 1
    for (int kc = 0; kc < 3; kc++) {
      {
        LDA4((2 * kc) * 4 + quad);
        MF16v(Pa0, Pa1, Pa2, Pa3);
      }
      Pa0 = *(const short8*)(q0 + (2 * kc + 2) * 512);
      Pa1 = *(const short8*)(q1 + (2 * kc + 2) * 512);
      Pa2 = *(const short8*)(q2 + (2 * kc + 2) * 512);
      Pa3 = *(const short8*)(q3 + (2 * kc + 2) * 512);
      {
        LDA4((2 * kc + 1) * 4 + quad);
        MF16v(Pb0, Pb1, Pb2, Pb3);
      }
      Pb0 = *(const short8*)(q0 + (2 * kc + 3) * 512);
      Pb1 = *(const short8*)(q1 + (2 * kc + 3) * 512);
      Pb2 = *(const short8*)(q2 + (2 * kc + 3) * 512);
      Pb3 = *(const short8*)(q3 + (2 * kc + 3) * 512);
    }
    { LDA4(24 + quad); MF16v(Pa0, Pa1, Pa2, Pa3); }   // kq6
    { LDA4(28 + quad); MF16v(Pb0, Pb1, Pb2, Pb3); }   // kq7
    __syncthreads();                                        // barrier 2 (WAR)
    // refill ping-pong with B3 kq0/1 (lands during epilogue + barrier 3)
    {
      const u16* r0 = wpack + 65536 + (wv * 4 + 0) * 4096 + lane * 8;
      const u16* r1 = wpack + 65536 + (wv * 4 + 1) * 4096 + lane * 8;
      const u16* r2 = wpack + 65536 + (wv * 4 + 2) * 4096 + lane * 8;
      const u16* r3 = wpack + 65536 + (wv * 4 + 3) * 4096 + lane * 8;
      Pa0 = *(const short8*)(r0);       Pa1 = *(const short8*)(r1);
      Pa2 = *(const short8*)(r2);       Pa3 = *(const short8*)(r3);
      Pb0 = *(const short8*)(r0 + 512); Pb1 = *(const short8*)(r1 + 512);
      Pb2 = *(const short8*)(r2 + 512); Pb3 = *(const short8*)(r3 + 512);
    }
    EPIC(c00, 0, ng0, bi0); EPIC(c10, 1, ng0, bi0);
    EPIC(c20, 2, ng0, bi0); EPIC(c30, 3, ng0, bi0);
    EPIC(c01, 0, ng0 + 16, bi1); EPIC(c11, 1, ng0 + 16, bi1);
    EPIC(c21, 2, ng0 + 16, bi1); EPIC(c31, 3, ng0 + 16, bi1);
    EPIC(c02, 0, ng0 + 32, bi2); EPIC(c12, 1, ng0 + 32, bi2);
    EPIC(c22, 2, ng0 + 32, bi2); EPIC(c32, 3, ng0 + 32, bi2);
    EPIC(c03, 0, ng0 + 48, bi3); EPIC(c13, 1, ng0 + 48, bi3);
    EPIC(c23, 2, ng0 + 48, bi3); EPIC(c33, 3, ng0 + 48, bi3);
  }
  __syncthreads();                                          // barrier 3

  // ---- layer 3: h3 = relu(h2@W3 + b3) : in-place act ----
  {
    int ng0 = wv * 64 + l15;
    float bi0 = b3[ng0], bi1 = b3[ng0 + 16], bi2 = b3[ng0 + 32], bi3 = b3[ng0 + 48];
    const u16* r0 = wpack + 65536 + (wv * 4 + 0) * 4096 + lane * 8;
    const u16* r1 = wpack + 65536 + (wv * 4 + 1) * 4096 + lane * 8;
    const u16* r2 = wpack + 65536 + (wv * 4 + 2) * 4096 + lane * 8;
    const u16* r3 = wpack + 65536 + (wv * 4 + 3) * 4096 + lane * 8;
    f32x4 c00 = ZER4, c01 = ZER4, c02 = ZER4, c03 = ZER4;
    f32x4 c10 = ZER4, c11 = ZER4, c12 = ZER4, c13 = ZER4;
    f32x4 c20 = ZER4, c21 = ZER4, c22 = ZER4, c23 = ZER4;
    f32x4 c30 = ZER4, c31 = ZER4, c32 = ZER4, c33 = ZER4;
#pragma unroll 1
    for (int kc = 0; kc < 3; kc++) {
      {
        LDA4((2 * kc) * 4 + quad);
        MF16v(Pa0, Pa1, Pa2, Pa3);
      }
      Pa0 = *(const short8*)(r0 + (2 * kc + 2) * 512);
      Pa1 = *(const short8*)(r1 + (2 * kc + 2) * 512);
      Pa2 = *(const short8*)(r2 + (2 * kc + 2) * 512);
      Pa3 = *(const short8*)(r3 + (2 * kc + 2) * 512);
      {
        LDA4((2 * kc + 1) * 4 + quad);
        MF16v(Pb0, Pb1, Pb2, Pb3);
      }
      Pb0 = *(const short8*)(r0 + (2 * kc + 3) * 512);
      Pb1 = *(const short8*)(r1 + (2 * kc + 3) * 512);
      Pb2 = *(const short8*)(r2 + (2 * kc + 3) * 512);
      Pb3 = *(const short8*)(r3 + (2 * kc + 3) * 512);
    }
    { LDA4(24 + quad); MF16v(Pa0, Pa1, Pa2, Pa3); }
    { LDA4(28 + quad); MF16v(Pb0, Pb1, Pb2, Pb3); }
    __syncthreads();                                        // barrier 4 (WAR)
    // refill ping-pong with L4 kq0/1 (streams: W4 col0, W4 col1, Wd)
    {
      const u16* s0 = wpack + 131072 + (wv * 2 + 0) * 4096 + lane * 8;
      const u16* s1 = wpack + 131072 + (wv * 2 + 1) * 4096 + lane * 8;
      const u16* sD = wpack + 163840 + lane * 8;
      Pa0 = *(const short8*)(s0);       Pa1 = *(const short8*)(s1);
      Pa2 = *(const short8*)(sD);
      Pb0 = *(const short8*)(s0 + 512); Pb1 = *(const short8*)(s1 + 512);
      Pb2 = *(const short8*)(sD + 512);
    }
    EPIC(c00, 0, ng0, bi0); EPIC(c10, 1, ng0, bi0);
    EPIC(c20, 2, ng0, bi0); EPIC(c30, 3, ng0, bi0);
    EPIC(c01, 0, ng0 + 16, bi1); EPIC(c11, 1, ng0 + 16, bi1);
    EPIC(c21, 2, ng0 + 16, bi1); EPIC(c31, 3, ng0 + 16, bi1);
    EPIC(c02, 0, ng0 + 32, bi2); EPIC(c12, 1, ng0 + 32, bi2);
    EPIC(c22, 2, ng0 + 32, bi2); EPIC(c32, 3, ng0 + 32, bi2);
    EPIC(c03, 0, ng0 + 48, bi3); EPIC(c13, 1, ng0 + 48, bi3);
    EPIC(c23, 2, ng0 + 48, bi3); EPIC(c33, 3, ng0 + 48, bi3);
  }
  __syncthreads();                                          // barrier 5

  short8 W5f[4];                             // rgb B-frags (wave0 only)

  // ---- layer 4: h4 = relu(h3@W4 + vdir-term + b4) -> h4L; + fused density ----
  {
    float nrm = sqrtf(rdx * rdx + rdy * rdy + rdz * rdz) + 1e-8f;
    float v0 = rdx / nrm, v1 = rdy / nrm, v2 = rdz / nrm;
    int ng0 = wv * 32 + l15;
    int ng1 = ng0 + 16;
    float ad0 = b4[ng0] + v0 * W4[32768 + ng0] + v1 * W4[32896 + ng0] + v2 * W4[33024 + ng0];
    float ad1 = b4[ng1] + v0 * W4[32768 + ng1] + v1 * W4[32896 + ng1] + v2 * W4[33024 + ng1];
    const u16* s0 = wpack + 131072 + (wv * 2 + 0) * 4096 + lane * 8;
    const u16* s1 = wpack + 131072 + (wv * 2 + 1) * 4096 + lane * 8;
    const u16* sD = wpack + 163840 + lane * 8;
    f32x4 c00 = ZER4, c01 = ZER4;
    f32x4 c10 = ZER4, c11 = ZER4;
    f32x4 c20 = ZER4, c21 = ZER4;
    f32x4 c30 = ZER4, c31 = ZER4;
    f32x4 c40 = ZER4, c41 = ZER4, c42 = ZER4, c43 = ZER4;   // density
#pragma unroll 1
    for (int kc = 0; kc < 3; kc++) {
      {
        LDA4((2 * kc) * 4 + quad);
        MF12v(Pa0, Pa1, Pa2);
      }
      Pa0 = *(const short8*)(s0 + (2 * kc + 2) * 512);
      Pa1 = *(const short8*)(s1 + (2 * kc + 2) * 512);
      Pa2 = *(const short8*)(sD + (2 * kc + 2) * 512);
      {
        LDA4((2 * kc + 1) * 4 + quad);
        MF12v(Pb0, Pb1, Pb2);
      }
      Pb0 = *(const short8*)(s0 + (2 * kc + 3) * 512);
      Pb1 = *(const short8*)(s1 + (2 * kc + 3) * 512);
      Pb2 = *(const short8*)(sD + (2 * kc + 3) * 512);
    }
    { LDA4(24 + quad); MF12v(Pa0, Pa1, Pa2); }
    { LDA4(28 + quad); MF12v(Pb0, Pb1, Pb2); }
    if (wv == 0) {       // only wave 0 needs W5 (it computes all rgb)
      const u16* s5 = wpack + 167936 + lane * 8;
#pragma unroll
      for (int kq = 0; kq < 4; kq++) W5f[kq] = *(const short8*)(s5 + kq * 512);
    }
    EPIH(c00, 0, ng0, ad0); EPIH(c10, 1, ng0, ad0);
    EPIH(c20, 2, ng0, ad0); EPIH(c30, 3, ng0, ad0);
    EPIH(c01, 0, ng1, ad1); EPIH(c11, 1, ng1, ad1);
    EPIH(c21, 2, ng1, ad1); EPIH(c31, 3, ng1, ad1);
    if (wv == 0 && l15 == 0) {
#pragma unroll
      for (int r = 0; r < 4; r++) {
        dens[ 0 + quad * 4 + r] = c40[r];
        dens[16 + quad * 4 + r] = c41[r];
        dens[32 + quad * 4 + r] = c42[r];
        dens[48 + quad * 4 + r] = c43[r];
      }
    }
  }
  __syncthreads();                                          // barrier 6 (last)

  // ---- wave 0: rgb (all rows via MFMA from h4L) + compositing; waves 1-3 exit ----
  if (wv == 0) {
    {
      f32x4 cR0 = ZER4, cR1 = ZER4, cR2 = ZER4, cR3 = ZER4;
#pragma unroll
      for (int kq = 0; kq < 4; kq++) {
        LDA4H(kq * 4 + quad);
        cR0 = MFMA(av0, W5f[kq], cR0, 0, 0, 0);
        cR1 = MFMA(av1, W5f[kq], cR1, 0, 0, 0);
        cR2 = MFMA(av2, W5f[kq], cR2, 0, 0, 0);
        cR3 = MFMA(av3, W5f[kq], cR3, 0, 0, 0);
      }
      if (l15 < 3) {
        float b5v = b5[l15];
#pragma unroll
        for (int r = 0; r < 4; r++) {
          rgbL[( 0 + quad * 4 + r) * 4 + l15] = 1.f / (1.f + __expf(-(cR0[r] + b5v)));
          rgbL[(16 + quad * 4 + r) * 4 + l15] = 1.f / (1.f + __expf(-(cR1[r] + b5v)));
          rgbL[(32 + quad * 4 + r) * 4 + l15] = 1.f / (1.f + __expf(-(cR2[r] + b5v)));
          rgbL[(48 + quad * 4 + r) * 4 + l15] = 1.f / (1.f + __expf(-(cR3[r] + b5v)));
        }
      }
    }
    // compositing (zv recomputed per lane, identical expression -> bit-identical)
    {
      int j = lane;
      float tr = t_rand[ray * 64 + j];
      float zvj = zval(j, tr);
      float zvn = __shfl_down(zvj, 1);
      float dist = (j < 63) ? (zvn - zvj) : 1e10f;
      float bd0 = bd[0];
      float alpha = 1.f - __expf(-fmaxf(dens[j] + bd0, 0.f) * dist);
      float v = 1.f - alpha + 1e-10f;
      float pscan = v;
#pragma unroll
      for (int d = 1; d < 64; d <<= 1) {
        float o = __shfl_up(pscan, d);
        if (j >= d) pscan *= o;
      }
      float T = __shfl_up(pscan, 1);
      if (j == 0) T = 1.f;
      float w = alpha * T;
      float r0 = w * rgbL[j * 4 + 0];
      float r1 = w * rgbL[j * 4 + 1];
      float r2 = w * rgbL[j * 4 + 2];
      float dp = w * zvj;
      float ac = w;
#pragma unroll
      for (int d = 32; d; d >>= 1) {
        r0 += __shfl_down(r0, d);
        r1 += __shfl_down(r1, d);
        r2 += __shfl_down(r2, d);
        dp += __shfl_down(dp, d);
        ac += __shfl_down(ac, d);
      }
      if (j == 0) {
        float bg = 1.f - ac;
        out[ray * 3 + 0] = r0 + bg;
        out[ray * 3 + 1] = r1 + bg;
        out[ray * 3 + 2] = r2 + bg;
        out[NRAYS * 3 + ray] = dp;
        out[NRAYS * 4 + ray] = ac;
      }
    }
  }
}

extern "C" void kernel_launch(void* const* d_in, const int* in_sizes, int n_in,
                              void* d_out, int out_size, void* d_ws, size_t ws_size,
                              hipStream_t stream) {
  const float* rays_o = (const float*)d_in[0];
  const float* rays_d = (const float*)d_in[1];
  const float* t_rand = (const float*)d_in[2];
  const float* W1 = (const float*)d_in[3];
  const float* b1 = (const float*)d_in[4];
  const float* W2 = (const float*)d_in[5];
  const float* b2 = (const float*)d_in[6];
  const float* W3 = (const float*)d_in[7];
  const float* b3 = (const float*)d_in[8];
  const float* Wd = (const float*)d_in[9];
  const float* bd = (const float*)d_in[10];
  const float* W4 = (const float*)d_in[11];
  const float* b4 = (const float*)d_in[12];
  const float* W5 = (const float*)d_in[13];
  const float* b5 = (const float*)d_in[14];
  u16* wpack = (u16*)d_ws;
  float* out = (float*)d_out;

  pack_weights<<<696, 256, 0, stream>>>(W1, b1, W2, W3, W4, Wd, W5, wpack);
  nerf_fused<<<NRAYS, 256, 0, stream>>>(rays_o, rays_d, t_rand, b2, b3,
                                        bd, W4, b4, b5, wpack, out);
}

// Round 12
// 225.448 us; speedup vs baseline: 1.3478x; 1.3478x over previous
//
#include <hip/hip_runtime.h>
#include <stdint.h>

// R18: half-ray blocks -> 4 INDEPENDENT blocks/CU at 8-acc. R17 proved
// 3 blocks/CU reachable but 16-acc (64 VGPR) can't fit any budget < 256.
// Samples are independent rows through the MLP; only the composite scan
// couples them. Split each ray into 2 blocks of 32 samples:
//   - 8 acc/wave (2 row-tiles x 4 col-tiles) = 32 VGPR; worst phase ~105
//     << 128 budget of __launch_bounds__(256,4) -> 4 blocks/CU, 16 waves.
//   - LDS 25KB/block -> 100KB at 4 blocks, not binding.
//   - compositing in a 3rd tiny kernel reading {rgb,dens} f32x4 from ws
//     (4MB @ ws+1MB; wpack is 356KB).
//   - all phase machinery is R16's, row-tiles halved (LDA2/MF8v/MF6v),
//     B ping-pong depth-2 under unroll-1 (R9's spill-cap mechanism).
// Tripwires: (a) WRITE>40MB -> spill at 8-acc -> revert R13, stop.
// (b) clean + occ>=45% but main>=150us -> occupancy-invariant lifetime ->
// structural floor -> revert R13. Predict main 100-130 + comp ~15,
// e2e ~185-210 vs best 216.5.

#define NRAYS 4096

typedef unsigned short u16;
typedef __attribute__((ext_vector_type(8))) short short8;
typedef __attribute__((ext_vector_type(4))) float f32x4;

__device__ __forceinline__ u16 f2bf(float f) {
  union { float f; uint32_t i; } v; v.f = f;
  return (u16)((v.i + 0x7FFFu + ((v.i >> 16) & 1u)) >> 16);
}
__device__ __forceinline__ float bf2f(u16 u) {
  union { uint32_t i; float f; } v; v.i = ((uint32_t)u) << 16; return v.f;
}
// packed fp32->bf16 (RNE), bit-identical to f2bf
__device__ __forceinline__ uint32_t cvtpk(float lo, float hi) {
  uint32_t r;
  asm("v_cvt_pk_bf16_f32 %0, %1, %2" : "=v"(r) : "v"(lo), "v"(hi));
  return r;
}

// stratified z sample for slot j (textually identical everywhere)
__device__ __forceinline__ float zval(int j, float tr) {
  float fj = (float)j;
  float zj = 0.5f + 2.0f * (fj / 63.0f);
  float lower = (j == 0)  ? zj : 0.5f * (zj + (0.5f + 2.0f * ((fj - 1.0f) / 63.0f)));
  float upper = (j == 63) ? zj : 0.5f * (zj + (0.5f + 2.0f * ((fj + 1.0f) / 63.0f)));
  return lower + (upper - lower) * tr;
}

// fragment-contiguous index for a [N][K=256] tile (8 kq blocks)
__device__ __forceinline__ int fragidx(int n, int k) {
  return ((((n >> 4) * 8 + (k >> 5)) * 64 + ((k >> 3) & 3) * 16 + (n & 15)) << 3) + (k & 7);
}
// same for a [N][K=32] tile (1 kq block)
__device__ __forceinline__ int fragidx32(int n, int k) {
  return (((n >> 4) * 64 + ((k >> 3) & 3) * 16 + (n & 15)) << 3) + (k & 7);
}

// ---------------- weight pack (fp32 -> bf16 fragment tiles) ----------------
// ws (bf16): W2f @0, W3f @65536, W4f @131072, Wd-pad @163840, W5-pad @167936,
//            W1-pad @169984 (end 178176 = 356KB). smp f32x4 region @ +1MB.
__global__ void pack_weights(const float* __restrict__ W1, const float* __restrict__ b1,
                             const float* __restrict__ W2, const float* __restrict__ W3,
                             const float* __restrict__ W4, const float* __restrict__ Wd,
                             const float* __restrict__ W5, u16* __restrict__ ws) {
  int idx = blockIdx.x * 256 + threadIdx.x;   // grid covers exactly 178176
  float v;
  int dst;
  if (idx < 65536) {
    int k = idx >> 8, n = idx & 255;          // W2 row-major [k][n]
    v = W2[idx];
    dst = fragidx(n, k);
  } else if (idx < 131072) {
    int o = idx - 65536, k = o >> 8, n = o & 255;
    v = W3[o];
    dst = 65536 + fragidx(n, k);
  } else if (idx < 163840) {
    int o = idx - 131072, k = o >> 7, n = o & 127;  // W4 row-major [k][128]
    v = W4[o];
    dst = 131072 + fragidx(n, k);
  } else if (idx < 167936) {
    int o = idx - 163840, k = o >> 4, n = o & 15;   // Wd padded to 16 cols
    v = (n == 0) ? Wd[k] : 0.f;
    dst = 163840 + fragidx(n, k);
  } else if (idx < 169984) {
    int o = idx - 167936, k = o >> 4, n = o & 15;   // W5 padded to 16 cols
    v = (n < 3) ? W5[k * 3 + n] : 0.f;
    dst = 167936 + fragidx(n, k);
  } else {
    int o = idx - 169984, k = o >> 8, n = o & 255;  // W1-pad [256N][32K]
    if (k < 6)      v = W1[(k >> 1) * 256 + n];
    else if (k == 6) v = b1[n];
    else            v = 0.f;
    dst = 169984 + fragidx32(n, k);
  }
  ws[dst] = f2bf(v);
}

#define MFMA __builtin_amdgcn_mfma_f32_16x16x32_bf16
#define ZER4 (f32x4){0.f, 0.f, 0.f, 0.f}

// 2 A row-tile fragments for k-slice SQ from act [32][256]
#define LDA2(SQ)                                                               \
    short8 av0 = *(const short8*)(act + m0 * 256 + (((SQ) ^ (m0 & 31)) << 3)); \
    short8 av1 = *(const short8*)(act + m1 * 256 + (((SQ) ^ (m1 & 31)) << 3))

// 8 MFMA: 2 row-tiles x 4 B col-tiles
#define MF8v(B0, B1, B2_, B3_) do {                                          \
    c00 = MFMA(av0, B0, c00, 0, 0, 0); c10 = MFMA(av1, B0, c10, 0, 0, 0);    \
    c01 = MFMA(av0, B1, c01, 0, 0, 0); c11 = MFMA(av1, B1, c11, 0, 0, 0);    \
    c02 = MFMA(av0, B2_, c02, 0, 0, 0); c12 = MFMA(av1, B2_, c12, 0, 0, 0);  \
    c03 = MFMA(av0, B3_, c03, 0, 0, 0); c13 = MFMA(av1, B3_, c13, 0, 0, 0);  \
  } while (0)

// 6 MFMA: 2 row-tiles x (2 B col-tiles + density col)
#define MF6v(B0, B1, BD) do {                                                \
    c00 = MFMA(av0, B0, c00, 0, 0, 0); c10 = MFMA(av1, B0, c10, 0, 0, 0);    \
    c01 = MFMA(av0, B1, c01, 0, 0, 0); c11 = MFMA(av1, B1, c11, 0, 0, 0);    \
    c40 = MFMA(av0, BD, c40, 0, 0, 0); c41 = MFMA(av1, BD, c41, 0, 0, 0);    \
  } while (0)

// store one 16x16 C-tile into act [32][256]
#define EPIC(CV, mt, ng, addv) do {                                          \
    int su_ = ((ng) >> 3), so_ = ((ng) & 7);                                 \
    float f0_ = fmaxf((CV)[0] + (addv), 0.f);                                \
    float f1_ = fmaxf((CV)[1] + (addv), 0.f);                                \
    float f2_ = fmaxf((CV)[2] + (addv), 0.f);                                \
    float f3_ = fmaxf((CV)[3] + (addv), 0.f);                                \
    uint32_t p01_ = cvtpk(f0_, f1_), p23_ = cvtpk(f2_, f3_);                 \
    int mmb_ = (mt) * 16 + quad * 4;                                         \
    act[(mmb_ + 0) * 256 + ((su_ ^ ((mmb_ + 0) & 31)) << 3) + so_] = (u16)p01_;         \
    act[(mmb_ + 1) * 256 + ((su_ ^ ((mmb_ + 1) & 31)) << 3) + so_] = (u16)(p01_ >> 16); \
    act[(mmb_ + 2) * 256 + ((su_ ^ ((mmb_ + 2) & 31)) << 3) + so_] = (u16)p23_;         \
    act[(mmb_ + 3) * 256 + ((su_ ^ ((mmb_ + 3) & 31)) << 3) + so_] = (u16)(p23_ >> 16); \
  } while (0)

// store one 16x16 C-tile into h4L [32][128]
#define EPIH(CV, mt, ng, addv) do {                                          \
    int su_ = ((ng) >> 3), so_ = ((ng) & 7);                                 \
    float f0_ = fmaxf((CV)[0] + (addv), 0.f);                                \
    float f1_ = fmaxf((CV)[1] + (addv), 0.f);                                \
    float f2_ = fmaxf((CV)[2] + (addv), 0.f);                                \
    float f3_ = fmaxf((CV)[3] + (addv), 0.f);                                \
    uint32_t p01_ = cvtpk(f0_, f1_), p23_ = cvtpk(f2_, f3_);                 \
    int mmb_ = (mt) * 16 + quad * 4;                                         \
    h4L[(mmb_ + 0) * 128 + ((su_ ^ ((mmb_ + 0) & 15)) << 3) + so_] = (u16)p01_;         \
    h4L[(mmb_ + 1) * 128 + ((su_ ^ ((mmb_ + 1) & 15)) << 3) + so_] = (u16)(p01_ >> 16); \
    h4L[(mmb_ + 2) * 128 + ((su_ ^ ((mmb_ + 2) & 15)) << 3) + so_] = (u16)p23_;         \
    h4L[(mmb_ + 3) * 128 + ((su_ ^ ((mmb_ + 3) & 15)) << 3) + so_] = (u16)(p23_ >> 16); \
  } while (0)

// A-fragments from h4L [32][128], SQ in 0..15
#define LDA2H(SQ)                                                              \
    short8 av0 = *(const short8*)(h4L + m0 * 128 + (((SQ) ^ (m0 & 15)) << 3)); \
    short8 av1 = *(const short8*)(h4L + m1 * 128 + (((SQ) ^ (m1 & 15)) << 3))

// main kernel: one block = 32 samples (half a ray). Writes {rgb, dens} per
// sample to smp[]; compositing is a separate kernel.
__global__ void __launch_bounds__(256, 4) nerf_half(
    const float* __restrict__ rays_o, const float* __restrict__ rays_d,
    const float* __restrict__ t_rand,
    const float* __restrict__ b2, const float* __restrict__ b3,
    const float* __restrict__ W4, const float* __restrict__ b4,
    const float* __restrict__ b5,
    const u16* __restrict__ wpack, f32x4* __restrict__ smp) {
  __shared__ u16   act[32 * 256];    // 16 KB, in-place L1->L2->L3
  __shared__ u16   h4L[32 * 128];    // 8 KB, L4 output
  __shared__ float dens[32];
  __shared__ float rgbL[32 * 4];

  const int t = threadIdx.x;
  const int lane = t & 63;
  const int wv = t >> 6;        // 0..3
  const int quad = lane >> 4;
  const int l15 = lane & 15;
  const int blk = blockIdx.x;
  const int ray = blk >> 1, half = blk & 1;
  const int m0 = l15, m1 = l15 + 16;

  short8 Pa0, Pa1, Pa2, Pa3, Pb0, Pb1, Pb2, Pb3;   // B ping-pong (32 VGPR cap)

  // ---- prefetch W1 frag + B2 kq0/1 ----
  short8 W1f0, W1f1, W1f2, W1f3;
  {
    const u16* w1b = wpack + 169984 + (wv * 4) * 512 + lane * 8;
    W1f0 = *(const short8*)(w1b);
    W1f1 = *(const short8*)(w1b + 512);
    W1f2 = *(const short8*)(w1b + 1024);
    W1f3 = *(const short8*)(w1b + 1536);
  }
  const u16* q0 = wpack + (wv * 4 + 0) * 4096 + lane * 8;
  const u16* q1 = wpack + (wv * 4 + 1) * 4096 + lane * 8;
  const u16* q2 = wpack + (wv * 4 + 2) * 4096 + lane * 8;
  const u16* q3 = wpack + (wv * 4 + 3) * 4096 + lane * 8;
  Pa0 = *(const short8*)(q0);       Pa1 = *(const short8*)(q1);
  Pa2 = *(const short8*)(q2);       Pa3 = *(const short8*)(q3);
  Pb0 = *(const short8*)(q0 + 512); Pb1 = *(const short8*)(q1 + 512);
  Pb2 = *(const short8*)(q2 + 512); Pb3 = *(const short8*)(q3 + 512);

  const float rox = rays_o[ray * 3 + 0], roy = rays_o[ray * 3 + 1], roz = rays_o[ray * 3 + 2];
  const float rdx = rays_d[ray * 3 + 0], rdy = rays_d[ray * 3 + 1], rdz = rays_d[ray * 3 + 2];

  // ---- layer 1 via MFMA (rows = this block's 32 samples) ----
  {
    short8 avz = {0, 0, 0, 0, 0, 0, 0, 0};
    short8 av0 = avz, av1 = avz;
    if (quad == 0) {
#pragma unroll
      for (int r = 0; r < 2; r++) {
        int m = l15 + r * 16;
        int j = half * 32 + m;
        float tr = t_rand[ray * 64 + j];
        float zm = zval(j, tr);
        float px = rox + rdx * zm, py = roy + rdy * zm, pz = roz + rdz * zm;
        u16 xh = f2bf(px); float xl = px - bf2f(xh);
        u16 yh = f2bf(py); float yl = py - bf2f(yh);
        u16 zh = f2bf(pz); float zl = pz - bf2f(zh);
        short8 f;
        f[0] = (short)xh; f[1] = (short)f2bf(xl);
        f[2] = (short)yh; f[3] = (short)f2bf(yl);
        f[4] = (short)zh; f[5] = (short)f2bf(zl);
        f[6] = (short)0x3F80; f[7] = 0;
        if (r == 0) av0 = f; else av1 = f;
      }
    }
    f32x4 c00 = ZER4, c01 = ZER4, c02 = ZER4, c03 = ZER4;
    f32x4 c10 = ZER4, c11 = ZER4, c12 = ZER4, c13 = ZER4;
    MF8v(W1f0, W1f1, W1f2, W1f3);
    int ng0 = wv * 64 + l15;
    EPIC(c00, 0, ng0, 0.f); EPIC(c10, 1, ng0, 0.f);
    EPIC(c01, 0, ng0 + 16, 0.f); EPIC(c11, 1, ng0 + 16, 0.f);
    EPIC(c02, 0, ng0 + 32, 0.f); EPIC(c12, 1, ng0 + 32, 0.f);
    EPIC(c03, 0, ng0 + 48, 0.f); EPIC(c13, 1, ng0 + 48, 0.f);
  }
  __syncthreads();                                          // barrier 1

  // ---- layer 2: in-place act ----
  {
    int ng0 = wv * 64 + l15;
    float bi0 = b2[ng0], bi1 = b2[ng0 + 16], bi2 = b2[ng0 + 32], bi3 = b2[ng0 + 48];
    f32x4 c00 = ZER4, c01 = ZER4, c02 = ZER4, c03 = ZER4;
    f32x4 c10 = ZER4, c11 = ZER4, c12 = ZER4, c13 = ZER4;
#pragma unroll 1
    for (int kc = 0; kc < 3; kc++) {
      { LDA2((2 * kc) * 4 + quad); MF8v(Pa0, Pa1, Pa2, Pa3); }
      Pa0 = *(const short8*)(q0 + (2 * kc + 2) * 512);
      Pa1 = *(const short8*)(q1 + (2 * kc + 2) * 512);
      Pa2 = *(const short8*)(q2 + (2 * kc + 2) * 512);
      Pa3 = *(const short8*)(q3 + (2 * kc + 2) * 512);
      { LDA2((2 * kc + 1) * 4 + quad); MF8v(Pb0, Pb1, Pb2, Pb3); }
      Pb0 = *(const short8*)(q0 + (2 * kc + 3) * 512);
      Pb1 = *(const short8*)(q1 + (2 * kc + 3) * 512);
      Pb2 = *(const short8*)(q2 + (2 * kc + 3) * 512);
      Pb3 = *(const short8*)(q3 + (2 * kc + 3) * 512);
    }
    { LDA2(24 + quad); MF8v(Pa0, Pa1, Pa2, Pa3); }
    { LDA2(28 + quad); MF8v(Pb0, Pb1, Pb2, Pb3); }
    __syncthreads();                                        // barrier 2 (WAR)
    {
      const u16* r0 = wpack + 65536 + (wv * 4 + 0) * 4096 + lane * 8;
      const u16* r1 = wpack + 65536 + (wv * 4 + 1) * 4096 + lane * 8;
      const u16* r2 = wpack + 65536 + (wv * 4 + 2) * 4096 + lane * 8;
      const u16* r3 = wpack + 65536 + (wv * 4 + 3) * 4096 + lane * 8;
      Pa0 = *(const short8*)(r0);       Pa1 = *(const short8*)(r1);
      Pa2 = *(const short8*)(r2);       Pa3 = *(const short8*)(r3);
      Pb0 = *(const short8*)(r0 + 512); Pb1 = *(const short8*)(r1 + 512);
      Pb2 = *(const short8*)(r2 + 512); Pb3 = *(const short8*)(r3 + 512);
    }
    EPIC(c00, 0, ng0, bi0); EPIC(c10, 1, ng0, bi0);
    EPIC(c01, 0, ng0 + 16, bi1); EPIC(c11, 1, ng0 + 16, bi1);
    EPIC(c02, 0, ng0 + 32, bi2); EPIC(c12, 1, ng0 + 32, bi2);
    EPIC(c03, 0, ng0 + 48, bi3); EPIC(c13, 1, ng0 + 48, bi3);
  }
  __syncthreads();                                          // barrier 3

  // ---- layer 3: in-place act ----
  {
    int ng0 = wv * 64 + l15;
    float bi0 = b3[ng0], bi1 = b3[ng0 + 16], bi2 = b3[ng0 + 32], bi3 = b3[ng0 + 48];
    const u16* r0 = wpack + 65536 + (wv * 4 + 0) * 4096 + lane * 8;
    const u16* r1 = wpack + 65536 + (wv * 4 + 1) * 4096 + lane * 8;
    const u16* r2 = wpack + 65536 + (wv * 4 + 2) * 4096 + lane * 8;
    const u16* r3 = wpack + 65536 + (wv * 4 + 3) * 4096 + lane * 8;
    f32x4 c00 = ZER4, c01 = ZER4, c02 = ZER4, c03 = ZER4;
    f32x4 c10 = ZER4, c11 = ZER4, c12 = ZER4, c13 = ZER4;
#pragma unroll 1
    for (int kc = 0; kc < 3; kc++) {
      { LDA2((2 * kc) * 4 + quad); MF8v(Pa0, Pa1, Pa2, Pa3); }
      Pa0 = *(const short8*)(r0 + (2 * kc + 2) * 512);
      Pa1 = *(const short8*)(r1 + (2 * kc + 2) * 512);
      Pa2 = *(const short8*)(r2 + (2 * kc + 2) * 512);
      Pa3 = *(const short8*)(r3 + (2 * kc + 2) * 512);
      { LDA2((2 * kc + 1) * 4 + quad); MF8v(Pb0, Pb1, Pb2, Pb3); }
      Pb0 = *(const short8*)(r0 + (2 * kc + 3) * 512);
      Pb1 = *(const short8*)(r1 + (2 * kc + 3) * 512);
      Pb2 = *(const short8*)(r2 + (2 * kc + 3) * 512);
      Pb3 = *(const short8*)(r3 + (2 * kc + 3) * 512);
    }
    { LDA2(24 + quad); MF8v(Pa0, Pa1, Pa2, Pa3); }
    { LDA2(28 + quad); MF8v(Pb0, Pb1, Pb2, Pb3); }
    __syncthreads();                                        // barrier 4 (WAR)
    {
      const u16* s0 = wpack + 131072 + (wv * 2 + 0) * 4096 + lane * 8;
      const u16* s1 = wpack + 131072 + (wv * 2 + 1) * 4096 + lane * 8;
      const u16* sD = wpack + 163840 + lane * 8;
      Pa0 = *(const short8*)(s0);       Pa1 = *(const short8*)(s1);
      Pa2 = *(const short8*)(sD);
      Pb0 = *(const short8*)(s0 + 512); Pb1 = *(const short8*)(s1 + 512);
      Pb2 = *(const short8*)(sD + 512);
    }
    EPIC(c00, 0, ng0, bi0); EPIC(c10, 1, ng0, bi0);
    EPIC(c01, 0, ng0 + 16, bi1); EPIC(c11, 1, ng0 + 16, bi1);
    EPIC(c02, 0, ng0 + 32, bi2); EPIC(c12, 1, ng0 + 32, bi2);
    EPIC(c03, 0, ng0 + 48, bi3); EPIC(c13, 1, ng0 + 48, bi3);
  }
  __syncthreads();                                          // barrier 5

  short8 W5f[4];                             // rgb B-frags (wave0 only)

  // ---- layer 4 -> h4L; + fused density ----
  {
    float nrm = sqrtf(rdx * rdx + rdy * rdy + rdz * rdz) + 1e-8f;
    float v0 = rdx / nrm, v1 = rdy / nrm, v2 = rdz / nrm;
    int ng0 = wv * 32 + l15;
    int ng1 = ng0 + 16;
    float ad0 = b4[ng0] + v0 * W4[32768 + ng0] + v1 * W4[32896 + ng0] + v2 * W4[33024 + ng0];
    float ad1 = b4[ng1] + v0 * W4[32768 + ng1] + v1 * W4[32896 + ng1] + v2 * W4[33024 + ng1];
    const u16* s0 = wpack + 131072 + (wv * 2 + 0) * 4096 + lane * 8;
    const u16* s1 = wpack + 131072 + (wv * 2 + 1) * 4096 + lane * 8;
    const u16* sD = wpack + 163840 + lane * 8;
    f32x4 c00 = ZER4, c01 = ZER4;
    f32x4 c10 = ZER4, c11 = ZER4;
    f32x4 c40 = ZER4, c41 = ZER4;            // density (rows 0-15 / 16-31)
#pragma unroll 1
    for (int kc = 0; kc < 3; kc++) {
      { LDA2((2 * kc) * 4 + quad); MF6v(Pa0, Pa1, Pa2); }
      Pa0 = *(const short8*)(s0 + (2 * kc + 2) * 512);
      Pa1 = *(const short8*)(s1 + (2 * kc + 2) * 512);
      Pa2 = *(const short8*)(sD + (2 * kc + 2) * 512);
      { LDA2((2 * kc + 1) * 4 + quad); MF6v(Pb0, Pb1, Pb2); }
      Pb0 = *(const short8*)(s0 + (2 * kc + 3) * 512);
      Pb1 = *(const short8*)(s1 + (2 * kc + 3) * 512);
      Pb2 = *(const short8*)(sD + (2 * kc + 3) * 512);
    }
    { LDA2(24 + quad); MF6v(Pa0, Pa1, Pa2); }
    { LDA2(28 + quad); MF6v(Pb0, Pb1, Pb2); }
    if (wv == 0) {
      const u16* s5 = wpack + 167936 + lane * 8;
#pragma unroll
      for (int kq = 0; kq < 4; kq++) W5f[kq] = *(const short8*)(s5 + kq * 512);
    }
    EPIH(c00, 0, ng0, ad0); EPIH(c10, 1, ng0, ad0);
    EPIH(c01, 0, ng1, ad1); EPIH(c11, 1, ng1, ad1);
    if (wv == 0 && l15 == 0) {
#pragma unroll
      for (int r = 0; r < 4; r++) {
        dens[ 0 + quad * 4 + r] = c40[r];
        dens[16 + quad * 4 + r] = c41[r];
      }
    }
  }
  __syncthreads();                                          // barrier 6 (last)

  // ---- wave 0: rgb via MFMA from h4L; write {rgb,dens} to smp ----
  if (wv == 0) {
    f32x4 cR0 = ZER4, cR1 = ZER4;
#pragma unroll
    for (int kq = 0; kq < 4; kq++) {
      LDA2H(kq * 4 + quad);
      cR0 = MFMA(av0, W5f[kq], cR0, 0, 0, 0);
      cR1 = MFMA(av1, W5f[kq], cR1, 0, 0, 0);
    }
    if (l15 < 3) {
      float b5v = b5[l15];
#pragma unroll
      for (int r = 0; r < 4; r++) {
        rgbL[( 0 + quad * 4 + r) * 4 + l15] = 1.f / (1.f + __expf(-(cR0[r] + b5v)));
        rgbL[(16 + quad * 4 + r) * 4 + l15] = 1.f / (1.f + __expf(-(cR1[r] + b5v)));
      }
    }
    int j = lane;
    if (j < 32) {     // same-wave LDS write->read (proven pattern, R14-R16)
      f32x4 v;
      v[0] = rgbL[j * 4 + 0];
      v[1] = rgbL[j * 4 + 1];
      v[2] = rgbL[j * 4 + 2];
      v[3] = dens[j];
      smp[ray * 64 + half * 32 + j] = v;
    }
  }
}

// ---- compositing: one 64-lane wave per ray ----
__global__ void __launch_bounds__(256) composite(
    const float* __restrict__ t_rand, const float* __restrict__ bd,
    const f32x4* __restrict__ smp, float* __restrict__ out) {
  int t = threadIdx.x;
  int ray = blockIdx.x * 4 + (t >> 6);
  int j = t & 63;
  f32x4 v = smp[ray * 64 + j];
  float tr = t_rand[ray * 64 + j];
  float zvj = zval(j, tr);
  float zvn = __shfl_down(zvj, 1);
  float dist = (j < 63) ? (zvn - zvj) : 1e10f;
  float alpha = 1.f - __expf(-fmaxf(v[3] + bd[0], 0.f) * dist);
  float vv = 1.f - alpha + 1e-10f;
  float pscan = vv;
#pragma unroll
  for (int d = 1; d < 64; d <<= 1) {
    float o = __shfl_up(pscan, d);
    if (j >= d) pscan *= o;
  }
  float T = __shfl_up(pscan, 1);
  if (j == 0) T = 1.f;
  float w = alpha * T;
  float r0 = w * v[0];
  float r1 = w * v[1];
  float r2 = w * v[2];
  float dp = w * zvj;
  float ac = w;
#pragma unroll
  for (int d = 32; d; d >>= 1) {
    r0 += __shfl_down(r0, d);
    r1 += __shfl_down(r1, d);
    r2 += __shfl_down(r2, d);
    dp += __shfl_down(dp, d);
    ac += __shfl_down(ac, d);
  }
  if (j == 0) {
    float bg = 1.f - ac;
    out[ray * 3 + 0] = r0 + bg;
    out[ray * 3 + 1] = r1 + bg;
    out[ray * 3 + 2] = r2 + bg;
    out[NRAYS * 3 + ray] = dp;
    out[NRAYS * 4 + ray] = ac;
  }
}

extern "C" void kernel_launch(void* const* d_in, const int* in_sizes, int n_in,
                              void* d_out, int out_size, void* d_ws, size_t ws_size,
                              hipStream_t stream) {
  const float* rays_o = (const float*)d_in[0];
  const float* rays_d = (const float*)d_in[1];
  const float* t_rand = (const float*)d_in[2];
  const float* W1 = (const float*)d_in[3];
  const float* b1 = (const float*)d_in[4];
  const float* W2 = (const float*)d_in[5];
  const float* b2 = (const float*)d_in[6];
  const float* W3 = (const float*)d_in[7];
  const float* b3 = (const float*)d_in[8];
  const float* Wd = (const float*)d_in[9];
  const float* bd = (const float*)d_in[10];
  const float* W4 = (const float*)d_in[11];
  const float* b4 = (const float*)d_in[12];
  const float* W5 = (const float*)d_in[13];
  const float* b5 = (const float*)d_in[14];
  u16* wpack = (u16*)d_ws;
  f32x4* smp = (f32x4*)((char*)d_ws + (1 << 20));   // 4 MB region @ +1MB
  float* out = (float*)d_out;

  pack_weights<<<696, 256, 0, stream>>>(W1, b1, W2, W3, W4, Wd, W5, wpack);
  nerf_half<<<NRAYS * 2, 256, 0, stream>>>(rays_o, rays_d, t_rand, b2, b3,
                                           W4, b4, b5, wpack, smp);
  composite<<<NRAYS / 4, 256, 0, stream>>>(t_rand, bd, smp, out);
}

// Round 13
// 217.190 us; speedup vs baseline: 1.3991x; 1.0380x over previous
//
#include <hip/hip_runtime.h>
#include <stdint.h>

// R19 = R13 verbatim (pre-registered revert; best measured: kernel 153.7us,
// e2e 216.5us). R18's occupancy sweep closed the search space:
//   - occupancy 22.6/30.5/40% -> kernel 154/250(spill)/163us: NOT the lever.
//   - half-ray blocks double weight L2 traffic (2.75GB -> ~80us L2 floor):
//     smaller blocks are L2-weight-bound.
//   - 2-ray blocks need 16-acc at >2 blocks/CU: proven spill (R7/8/15/17).
// ~154us kernel is the structural floor of the fused design: barrier-phased
// dependent-latency chains at 2-deep overlap, all deletable links deleted
// (MfmaUtil 26%, bank-conflict 0, spill 0, density/rgb/L1 via MFMA).
// R13 structure: (256,2) envelope, 16 acc, act A/B double-buffer, 6 barriers,
// fragment-contiguous B bursts, full-B2 + 4-deep B3 + 2-deep L4 prefetch.

#define NRAYS 4096

typedef unsigned short u16;
typedef __attribute__((ext_vector_type(8))) short short8;
typedef __attribute__((ext_vector_type(4))) float f32x4;
typedef __attribute__((ext_vector_type(4))) unsigned int uint32x4;

__device__ __forceinline__ u16 f2bf(float f) {
  union { float f; uint32_t i; } v; v.f = f;
  return (u16)((v.i + 0x7FFFu + ((v.i >> 16) & 1u)) >> 16);
}
__device__ __forceinline__ float bf2f(u16 u) {
  union { uint32_t i; float f; } v; v.i = ((uint32_t)u) << 16; return v.f;
}
// packed fp32->bf16 (RNE), lo -> bits 15:0, hi -> bits 31:16 (bit-identical to f2bf)
__device__ __forceinline__ uint32_t cvtpk(float lo, float hi) {
  uint32_t r;
  asm("v_cvt_pk_bf16_f32 %0, %1, %2" : "=v"(r) : "v"(lo), "v"(hi));
  return r;
}

// fragment-contiguous index for W^T: element (n, k) of an [N][K] tile ->
// block (nt = n>>4, kq = k>>5), lane = ((k>>3)&3)*16 + (n&15), elem j = k&7.
// Wave load at (nt,kq) = 64 lanes x 16B = 1KB contiguous.
__device__ __forceinline__ int fragidx(int n, int k) {
  return ((((n >> 4) * 8 + (k >> 5)) * 64 + ((k >> 3) & 3) * 16 + (n & 15)) << 3) + (k & 7);
}

// ---------------- weight transpose + fp32->bf16 convert into workspace ----------------
// ws (bf16 elems): W2f @0 (65536), W3f @65536 (65536), W4f @131072 (32768),
//                  Wd-pad @163840 (4096: [256K][16N], col0=Wd),
//                  W5-pad @167936 (2048: [128K][16N], cols0-2=W5)
__global__ void pack_weights(const float* __restrict__ W2, const float* __restrict__ W3,
                             const float* __restrict__ W4, const float* __restrict__ Wd,
                             const float* __restrict__ W5, u16* __restrict__ ws) {
  int idx = blockIdx.x * 256 + threadIdx.x;   // grid covers exactly 169984
  float v;
  int dst;
  if (idx < 65536) {
    int k = idx >> 8, n = idx & 255;          // W2 row-major [k][n]
    v = W2[idx];
    dst = fragidx(n, k);
  } else if (idx < 131072) {
    int o = idx - 65536, k = o >> 8, n = o & 255;
    v = W3[o];
    dst = 65536 + fragidx(n, k);
  } else if (idx < 163840) {
    int o = idx - 131072, k = o >> 7, n = o & 127;  // W4 row-major [k][128]
    v = W4[o];
    dst = 131072 + fragidx(n, k);
  } else if (idx < 167936) {
    int o = idx - 163840, k = o >> 4, n = o & 15;   // Wd [256][1] padded to 16 cols
    v = (n == 0) ? Wd[k] : 0.f;
    dst = 163840 + fragidx(n, k);
  } else {
    int o = idx - 167936, k = o >> 4, n = o & 15;   // W5 [128][3] padded to 16 cols
    v = (n < 3) ? W5[k * 3 + n] : 0.f;
    dst = 167936 + fragidx(n, k);
  }
  ws[dst] = f2bf(v);
}

#define MFMA __builtin_amdgcn_mfma_f32_16x16x32_bf16
#define ZER4 (f32x4){0.f, 0.f, 0.f, 0.f}

// declare + load the 4 A row-tile fragments for k-slice SQ from ACT
#define LDA4(ACT, SQ)                                                          \
    short8 av0 = *(const short8*)((ACT) + m0 * 256 + (((SQ) ^ (m0 & 31)) << 3)); \
    short8 av1 = *(const short8*)((ACT) + m1 * 256 + (((SQ) ^ (m1 & 31)) << 3)); \
    short8 av2 = *(const short8*)((ACT) + m2 * 256 + (((SQ) ^ (m2 & 31)) << 3)); \
    short8 av3 = *(const short8*)((ACT) + m3 * 256 + (((SQ) ^ (m3 & 31)) << 3))

// 16 MFMA: 4 row-tiles (av0..av3) x 4 B col-tiles (args)
#define MF16v(B0, B1, B2_, B3_) do {                                         \
    c00 = MFMA(av0, B0, c00, 0, 0, 0); c10 = MFMA(av1, B0, c10, 0, 0, 0);    \
    c20 = MFMA(av2, B0, c20, 0, 0, 0); c30 = MFMA(av3, B0, c30, 0, 0, 0);    \
    c01 = MFMA(av0, B1, c01, 0, 0, 0); c11 = MFMA(av1, B1, c11, 0, 0, 0);    \
    c21 = MFMA(av2, B1, c21, 0, 0, 0); c31 = MFMA(av3, B1, c31, 0, 0, 0);    \
    c02 = MFMA(av0, B2_, c02, 0, 0, 0); c12 = MFMA(av1, B2_, c12, 0, 0, 0);  \
    c22 = MFMA(av2, B2_, c22, 0, 0, 0); c32 = MFMA(av3, B2_, c32, 0, 0, 0);  \
    c03 = MFMA(av0, B3_, c03, 0, 0, 0); c13 = MFMA(av1, B3_, c13, 0, 0, 0);  \
    c23 = MFMA(av2, B3_, c23, 0, 0, 0); c33 = MFMA(av3, B3_, c33, 0, 0, 0);  \
  } while (0)

// store one 16x16 C-tile (f32x4 CV), row-tile mt, column ng, into swizzled ACT
#define EPIC(CV, mt, ng, addv, ACT) do {                                     \
    int su_ = ((ng) >> 3), so_ = ((ng) & 7);                                 \
    float f0_ = fmaxf((CV)[0] + (addv), 0.f);                                \
    float f1_ = fmaxf((CV)[1] + (addv), 0.f);                                \
    float f2_ = fmaxf((CV)[2] + (addv), 0.f);                                \
    float f3_ = fmaxf((CV)[3] + (addv), 0.f);                                \
    uint32_t p01_ = cvtpk(f0_, f1_), p23_ = cvtpk(f2_, f3_);                 \
    int mmb_ = (mt) * 16 + quad * 4;                                         \
    (ACT)[(mmb_ + 0) * 256 + ((su_ ^ ((mmb_ + 0) & 31)) << 3) + so_] = (u16)p01_;         \
    (ACT)[(mmb_ + 1) * 256 + ((su_ ^ ((mmb_ + 1) & 31)) << 3) + so_] = (u16)(p01_ >> 16); \
    (ACT)[(mmb_ + 2) * 256 + ((su_ ^ ((mmb_ + 2) & 31)) << 3) + so_] = (u16)p23_;         \
    (ACT)[(mmb_ + 3) * 256 + ((su_ ^ ((mmb_ + 3) & 31)) << 3) + so_] = (u16)(p23_ >> 16); \
  } while (0)

__global__ void __launch_bounds__(256, 2) nerf_fused(
    const float* __restrict__ rays_o, const float* __restrict__ rays_d,
    const float* __restrict__ t_rand,
    const float* __restrict__ W1, const float* __restrict__ b1,
    const float* __restrict__ b2, const float* __restrict__ b3,
    const float* __restrict__ bd,
    const float* __restrict__ W4, const float* __restrict__ b4,
    const float* __restrict__ b5,
    const u16* __restrict__ wpack, float* __restrict__ out) {
  __shared__ u16   actA[64 * 256];   // 32 KB, XOR-swizzled slots (ping)
  __shared__ u16   actB[64 * 256];   // 32 KB (pong)
  __shared__ float w1L[1040];        // 4 KB: (k+p)-skewed [W1r0,W1r1,W1r2,b1] per col
  __shared__ float zv[64];
  __shared__ float dist[64];
  __shared__ float dens[64];
  __shared__ float rgbL[64 * 4];
  __shared__ float vdirL[4];
  __shared__ float b5L[4];

  const int t = threadIdx.x;
  const int lane = t & 63;
  const int wv = t >> 6;        // 0..3
  const int quad = lane >> 4;
  const int l15 = lane & 15;
  const int ray = blockIdx.x;
  const int m0 = l15, m1 = l15 + 16, m2 = l15 + 32, m3 = l15 + 48;

  // ---- L2 B full prefetch: issued first, completes under setup+L1 ----
  short8 B2a[8], B2b[8], B2c[8], B2d[8];
  {
    const u16* q0 = wpack + (wv * 4 + 0) * 4096 + lane * 8;
    const u16* q1 = wpack + (wv * 4 + 1) * 4096 + lane * 8;
    const u16* q2 = wpack + (wv * 4 + 2) * 4096 + lane * 8;
    const u16* q3 = wpack + (wv * 4 + 3) * 4096 + lane * 8;
#pragma unroll
    for (int kq = 0; kq < 8; kq++) {
      B2a[kq] = *(const short8*)(q0 + kq * 512);
      B2b[kq] = *(const short8*)(q1 + kq * 512);
      B2c[kq] = *(const short8*)(q2 + kq * 512);
      B2d[kq] = *(const short8*)(q3 + kq * 512);
    }
  }

  // ---- setup ----
  if (t < 64) {
    int j = t;
    float fj = (float)j;
    float zj = 0.5f + 2.0f * (fj / 63.0f);
    float lower = (j == 0)  ? zj : 0.5f * (zj + (0.5f + 2.0f * ((fj - 1.0f) / 63.0f)));
    float upper = (j == 63) ? zj : 0.5f * (zj + (0.5f + 2.0f * ((fj + 1.0f) / 63.0f)));
    float tr = t_rand[ray * 64 + j];
    zv[j] = lower + (upper - lower) * tr;
  }
  // W1/b1 -> LDS, skewed: col k lives at float offset (k + (k>>6))*4
  {
    int base = (t + (t >> 6)) * 4;
    w1L[base + 0] = W1[t];
    w1L[base + 1] = W1[256 + t];
    w1L[base + 2] = W1[512 + t];
    w1L[base + 3] = b1[t];
  }
  if (t < 3) b5L[t] = b5[t];
  if (t == 3) b5L[3] = bd[0];
  if (t == 0) {
    float dx = rays_d[ray * 3 + 0];
    float dy = rays_d[ray * 3 + 1];
    float dz = rays_d[ray * 3 + 2];
    float nrm = sqrtf(dx * dx + dy * dy + dz * dz) + 1e-8f;
    vdirL[0] = dx / nrm; vdirL[1] = dy / nrm; vdirL[2] = dz / nrm;
  }
  __syncthreads();                                          // barrier 1

  if (t < 64) dist[t] = (t < 63) ? (zv[t + 1] - zv[t]) : 1e10f;

  // ---- layer 1: h1 = relu(pts@W1 + b1) -> actA (coeffs from LDS) ----
  {
    int m = t >> 2, p = t & 3;
    float zm = zv[m];
    float px = rays_o[ray * 3 + 0] + rays_d[ray * 3 + 0] * zm;
    float py = rays_o[ray * 3 + 1] + rays_d[ray * 3 + 1] * zm;
    float pz = rays_o[ray * 3 + 2] + rays_d[ray * 3 + 2] * zm;
#pragma unroll 1
    for (int kk = 0; kk < 64; kk += 8) {
      float r[8];
#pragma unroll
      for (int j = 0; j < 8; j++) {
        int k = p * 64 + kk + j;
        f32x4 w = *(const f32x4*)(w1L + (k + p) * 4);
        r[j] = fmaxf(w[3] + px * w[0] + py * w[1] + pz * w[2], 0.f);
      }
      uint32x4 pk;
      pk[0] = cvtpk(r[0], r[1]);
      pk[1] = cvtpk(r[2], r[3]);
      pk[2] = cvtpk(r[4], r[5]);
      pk[3] = cvtpk(r[6], r[7]);
      int k0 = p * 64 + kk;
      int u = (k0 >> 3) ^ (m & 31);
      *(uint32x4*)(actA + m * 256 + u * 8) = pk;
    }
  }
  __syncthreads();                                          // barrier 2

  short8 B3a[4], B3b[4], B3c[4], B3d[4];     // L3 kq0-3 prefetch (filled in L2)

  // ---- layer 2: h2 = relu(h1@W2 + b2) : reads actA, writes actB ----
  {
    int ng0 = wv * 64 + l15;
    float bi0 = b2[ng0], bi1 = b2[ng0 + 16], bi2 = b2[ng0 + 32], bi3 = b2[ng0 + 48];
    f32x4 c00 = ZER4, c01 = ZER4, c02 = ZER4, c03 = ZER4;
    f32x4 c10 = ZER4, c11 = ZER4, c12 = ZER4, c13 = ZER4;
    f32x4 c20 = ZER4, c21 = ZER4, c22 = ZER4, c23 = ZER4;
    f32x4 c30 = ZER4, c31 = ZER4, c32 = ZER4, c33 = ZER4;
#pragma unroll
    for (int kq = 0; kq < 8; kq++) {
      LDA4(actA, kq * 4 + quad);
      MF16v(B2a[kq], B2b[kq], B2c[kq], B2d[kq]);
    }
    // prefetch L3 B kq0-3 (lands during epilogue + barrier drain)
    {
      const u16* r0 = wpack + 65536 + (wv * 4 + 0) * 4096 + lane * 8;
      const u16* r1 = wpack + 65536 + (wv * 4 + 1) * 4096 + lane * 8;
      const u16* r2 = wpack + 65536 + (wv * 4 + 2) * 4096 + lane * 8;
      const u16* r3 = wpack + 65536 + (wv * 4 + 3) * 4096 + lane * 8;
#pragma unroll
      for (int kq = 0; kq < 4; kq++) {
        B3a[kq] = *(const short8*)(r0 + kq * 512);
        B3b[kq] = *(const short8*)(r1 + kq * 512);
        B3c[kq] = *(const short8*)(r2 + kq * 512);
        B3d[kq] = *(const short8*)(r3 + kq * 512);
      }
    }
    EPIC(c00, 0, ng0, bi0, actB); EPIC(c10, 1, ng0, bi0, actB);
    EPIC(c20, 2, ng0, bi0, actB); EPIC(c30, 3, ng0, bi0, actB);
    EPIC(c01, 0, ng0 + 16, bi1, actB); EPIC(c11, 1, ng0 + 16, bi1, actB);
    EPIC(c21, 2, ng0 + 16, bi1, actB); EPIC(c31, 3, ng0 + 16, bi1, actB);
    EPIC(c02, 0, ng0 + 32, bi2, actB); EPIC(c12, 1, ng0 + 32, bi2, actB);
    EPIC(c22, 2, ng0 + 32, bi2, actB); EPIC(c32, 3, ng0 + 32, bi2, actB);
    EPIC(c03, 0, ng0 + 48, bi3, actB); EPIC(c13, 1, ng0 + 48, bi3, actB);
    EPIC(c23, 2, ng0 + 48, bi3, actB); EPIC(c33, 3, ng0 + 48, bi3, actB);
  }
  __syncthreads();                                          // barrier 3

  short8 L4a[2], L4b[2], L4d[2];             // L4 kq0-1 prefetch (filled in L3)

  // ---- layer 3: h3 = relu(h2@W3 + b3) : reads actB, writes actA ----
  {
    int ng0 = wv * 64 + l15;
    float bi0 = b3[ng0], bi1 = b3[ng0 + 16], bi2 = b3[ng0 + 32], bi3 = b3[ng0 + 48];
    const u16* r0 = wpack + 65536 + (wv * 4 + 0) * 4096 + lane * 8;
    const u16* r1 = wpack + 65536 + (wv * 4 + 1) * 4096 + lane * 8;
    const u16* r2 = wpack + 65536 + (wv * 4 + 2) * 4096 + lane * 8;
    const u16* r3 = wpack + 65536 + (wv * 4 + 3) * 4096 + lane * 8;
    f32x4 c00 = ZER4, c01 = ZER4, c02 = ZER4, c03 = ZER4;
    f32x4 c10 = ZER4, c11 = ZER4, c12 = ZER4, c13 = ZER4;
    f32x4 c20 = ZER4, c21 = ZER4, c22 = ZER4, c23 = ZER4;
    f32x4 c30 = ZER4, c31 = ZER4, c32 = ZER4, c33 = ZER4;
#pragma unroll
    for (int kq = 0; kq < 8; kq++) {
      short8 b0, b1v, b2v, b3v;
      if (kq < 4) { b0 = B3a[kq]; b1v = B3b[kq]; b2v = B3c[kq]; b3v = B3d[kq]; }
      else {
        b0 = *(const short8*)(r0 + kq * 512);
        b1v = *(const short8*)(r1 + kq * 512);
        b2v = *(const short8*)(r2 + kq * 512);
        b3v = *(const short8*)(r3 + kq * 512);
      }
      LDA4(actB, kq * 4 + quad);
      MF16v(b0, b1v, b2v, b3v);
    }
    // prefetch L4 B kq0-1 + density-frag kq0-1
    {
      const u16* s0 = wpack + 131072 + (wv * 2 + 0) * 4096 + lane * 8;
      const u16* s1 = wpack + 131072 + (wv * 2 + 1) * 4096 + lane * 8;
      const u16* sD = wpack + 163840 + lane * 8;
#pragma unroll
      for (int kq = 0; kq < 2; kq++) {
        L4a[kq] = *(const short8*)(s0 + kq * 512);
        L4b[kq] = *(const short8*)(s1 + kq * 512);
        L4d[kq] = *(const short8*)(sD + kq * 512);
      }
    }
    EPIC(c00, 0, ng0, bi0, actA); EPIC(c10, 1, ng0, bi0, actA);
    EPIC(c20, 2, ng0, bi0, actA); EPIC(c30, 3, ng0, bi0, actA);
    EPIC(c01, 0, ng0 + 16, bi1, actA); EPIC(c11, 1, ng0 + 16, bi1, actA);
    EPIC(c21, 2, ng0 + 16, bi1, actA); EPIC(c31, 3, ng0 + 16, bi1, actA);
    EPIC(c02, 0, ng0 + 32, bi2, actA); EPIC(c12, 1, ng0 + 32, bi2, actA);
    EPIC(c22, 2, ng0 + 32, bi2, actA); EPIC(c32, 3, ng0 + 32, bi2, actA);
    EPIC(c03, 0, ng0 + 48, bi3, actA); EPIC(c13, 1, ng0 + 48, bi3, actA);
    EPIC(c23, 2, ng0 + 48, bi3, actA); EPIC(c33, 3, ng0 + 48, bi3, actA);
  }
  __syncthreads();                                          // barrier 4

  short8 W5f[4];                             // rgb B-frag prefetch (filled in L4)

  // ---- layer 4: h4 = relu(h3@W4 + vdir-term + b4), N=128; + fused density ----
  // reads actA, writes actB; density = h3@Wd as extra MFMA column (wave0 stores)
  {
    float v0 = vdirL[0], v1 = vdirL[1], v2 = vdirL[2];
    int ng0 = wv * 32 + l15;
    int ng1 = ng0 + 16;
    float ad0 = b4[ng0] + v0 * W4[32768 + ng0] + v1 * W4[32896 + ng0] + v2 * W4[33024 + ng0];
    float ad1 = b4[ng1] + v0 * W4[32768 + ng1] + v1 * W4[32896 + ng1] + v2 * W4[33024 + ng1];
    const u16* s0 = wpack + 131072 + (wv * 2 + 0) * 4096 + lane * 8;
    const u16* s1 = wpack + 131072 + (wv * 2 + 1) * 4096 + lane * 8;
    const u16* sD = wpack + 163840 + lane * 8;
    f32x4 c00 = ZER4, c01 = ZER4;
    f32x4 c10 = ZER4, c11 = ZER4;
    f32x4 c20 = ZER4, c21 = ZER4;
    f32x4 c30 = ZER4, c31 = ZER4;
    f32x4 c40 = ZER4, c41 = ZER4, c42 = ZER4, c43 = ZER4;   // density
#pragma unroll
    for (int kq = 0; kq < 8; kq++) {
      short8 b0 = (kq < 2) ? L4a[kq] : *(const short8*)(s0 + kq * 512);
      short8 b1v = (kq < 2) ? L4b[kq] : *(const short8*)(s1 + kq * 512);
      short8 bD = (kq < 2) ? L4d[kq] : *(const short8*)(sD + kq * 512);
      LDA4(actA, kq * 4 + quad);
      c00 = MFMA(av0, b0, c00, 0, 0, 0); c10 = MFMA(av1, b0, c10, 0, 0, 0);
      c20 = MFMA(av2, b0, c20, 0, 0, 0); c30 = MFMA(av3, b0, c30, 0, 0, 0);
      c01 = MFMA(av0, b1v, c01, 0, 0, 0); c11 = MFMA(av1, b1v, c11, 0, 0, 0);
      c21 = MFMA(av2, b1v, c21, 0, 0, 0); c31 = MFMA(av3, b1v, c31, 0, 0, 0);
      c40 = MFMA(av0, bD, c40, 0, 0, 0); c41 = MFMA(av1, bD, c41, 0, 0, 0);
      c42 = MFMA(av2, bD, c42, 0, 0, 0); c43 = MFMA(av3, bD, c43, 0, 0, 0);
    }
    // prefetch rgb W5 frag (lands during epilogue + barrier drain)
    {
      const u16* s5 = wpack + 167936 + lane * 8;
#pragma unroll
      for (int kq = 0; kq < 4; kq++) W5f[kq] = *(const short8*)(s5 + kq * 512);
    }
    EPIC(c00, 0, ng0, ad0, actB); EPIC(c10, 1, ng0, ad0, actB);
    EPIC(c20, 2, ng0, ad0, actB); EPIC(c30, 3, ng0, ad0, actB);
    EPIC(c01, 0, ng1, ad1, actB); EPIC(c11, 1, ng1, ad1, actB);
    EPIC(c21, 2, ng1, ad1, actB); EPIC(c31, 3, ng1, ad1, actB);
    // density: col 0 of the c4x tiles; wave 0, lanes l15==0 hold it
    if (wv == 0 && l15 == 0) {
#pragma unroll
      for (int r = 0; r < 4; r++) {
        dens[ 0 + quad * 4 + r] = c40[r];
        dens[16 + quad * 4 + r] = c41[r];
        dens[32 + quad * 4 + r] = c42[r];
        dens[48 + quad * 4 + r] = c43[r];
      }
    }
  }
  __syncthreads();                                          // barrier 5

  // ---- rgb = sigmoid(h4@W5 + b5) via MFMA, wave-split row-tiles ----
  {
    int mR = wv * 16 + l15;
    f32x4 cR = ZER4;
#pragma unroll
    for (int kq = 0; kq < 4; kq++) {
      short8 av = *(const short8*)(actB + mR * 256 + (((kq * 4 + quad) ^ (mR & 31)) << 3));
      cR = MFMA(av, W5f[kq], cR, 0, 0, 0);
    }
    if (l15 < 3) {
#pragma unroll
      for (int r = 0; r < 4; r++) {
        int row = wv * 16 + quad * 4 + r;
        rgbL[row * 4 + l15] = 1.f / (1.f + __expf(-(cR[r] + b5L[l15])));
      }
    }
  }
  __syncthreads();                                          // barrier 6

  // ---- alpha compositing: wave 0 handles the block's single ray ----
  if (t < 64) {
    int j = t;
    float alpha = 1.f - __expf(-fmaxf(dens[j] + b5L[3], 0.f) * dist[j]);
    float v = 1.f - alpha + 1e-10f;
    float pscan = v;
#pragma unroll
    for (int d = 1; d < 64; d <<= 1) {
      float o = __shfl_up(pscan, d);
      if (j >= d) pscan *= o;
    }
    float T = __shfl_up(pscan, 1);
    if (j == 0) T = 1.f;
    float w = alpha * T;
    float r0 = w * rgbL[j * 4 + 0];
    float r1 = w * rgbL[j * 4 + 1];
    float r2 = w * rgbL[j * 4 + 2];
    float dp = w * zv[j];
    float ac = w;
#pragma unroll
    for (int d = 32; d; d >>= 1) {
      r0 += __shfl_down(r0, d);
      r1 += __shfl_down(r1, d);
      r2 += __shfl_down(r2, d);
      dp += __shfl_down(dp, d);
      ac += __shfl_down(ac, d);
    }
    if (j == 0) {
      float bg = 1.f - ac;
      out[ray * 3 + 0] = r0 + bg;
      out[ray * 3 + 1] = r1 + bg;
      out[ray * 3 + 2] = r2 + bg;
      out[NRAYS * 3 + ray] = dp;
      out[NRAYS * 4 + ray] = ac;
    }
  }
}

extern "C" void kernel_launch(void* const* d_in, const int* in_sizes, int n_in,
                              void* d_out, int out_size, void* d_ws, size_t ws_size,
                              hipStream_t stream) {
  const float* rays_o = (const float*)d_in[0];
  const float* rays_d = (const float*)d_in[1];
  const float* t_rand = (const float*)d_in[2];
  const float* W1 = (const float*)d_in[3];
  const float* b1 = (const float*)d_in[4];
  const float* W2 = (const float*)d_in[5];
  const float* b2 = (const float*)d_in[6];
  const float* W3 = (const float*)d_in[7];
  const float* b3 = (const float*)d_in[8];
  const float* Wd = (const float*)d_in[9];
  const float* bd = (const float*)d_in[10];
  const float* W4 = (const float*)d_in[11];
  const float* b4 = (const float*)d_in[12];
  const float* W5 = (const float*)d_in[13];
  const float* b5 = (const float*)d_in[14];
  u16* wpack = (u16*)d_ws;
  float* out = (float*)d_out;

  pack_weights<<<664, 256, 0, stream>>>(W2, W3, W4, Wd, W5, wpack);
  nerf_fused<<<NRAYS, 256, 0, stream>>>(rays_o, rays_d, t_rand, W1, b1, b2, b3,
                                        bd, W4, b4, b5, wpack, out);
}